// Round 4
// baseline (310.778 us; speedup 1.0000x reference)
//
#include <hip/hip_runtime.h>
#include <math.h>

#define B_ 32768
#define D_ 512
#define E_ 64
#define K_ 4
#define H_ 5376
#define H4_ (H_ / 4)

typedef float f32x4 __attribute__((ext_vector_type(4)));

// Fused: gating GEMMs (f32 tile accum, f64 cross-tile fold) + top-5 + softmax
// gates + importance/load partials + output dispatch.
// Block = 256 threads handles 64 tokens. Thread (ti,te) = (t>>4, t&15) owns
// tokens {ti,ti+16,ti+32,ti+48} x experts {4te..4te+3}.
__global__ __launch_bounds__(256) void gate_out_kernel(
    const float* __restrict__ x,
    const float* __restrict__ wgate,
    const float* __restrict__ wnoise,
    const float* __restrict__ noise,
    const float* __restrict__ ctx,
    float* __restrict__ out,
    float* __restrict__ g_imp,
    float* __restrict__ g_load)
{
    __shared__ float4 xs4[64 * 17];   // x tile [64 tok][64 d], row padded (bank spread)
    __shared__ float4 wg4[64 * 16];   // w_gate tile [64 d][64 e]
    __shared__ float4 wn4[64 * 16];   // w_noise tile
    __shared__ float  s_imp[E_];
    __shared__ float  s_load[E_];
    __shared__ int    s_idx[64][4];
    __shared__ float  s_g[64][4];

    const int t  = threadIdx.x;
    const int te = t & 15;
    const int ti = t >> 4;
    const int b0 = blockIdx.x * 64;

    if (t < E_) { s_imp[t] = 0.0f; s_load[t] = 0.0f; }

    double acc_c[4][4];
    double acc_n[4][4];
#pragma unroll
    for (int q = 0; q < 4; ++q)
#pragma unroll
        for (int j = 0; j < 4; ++j) { acc_c[q][j] = 0.0; acc_n[q][j] = 0.0; }

    for (int kd = 0; kd < D_; kd += 64) {
        __syncthreads();   // protect LDS from previous iteration's readers
#pragma unroll
        for (int r = 0; r < 4; ++r) {
            int f   = t + 256 * r;
            int row = f >> 4;
            int c4  = f & 15;
            xs4[row * 17 + c4] = *(const float4*)&x[(size_t)(b0 + row) * D_ + kd + c4 * 4];
            wg4[row * 16 + c4] = *(const float4*)&wgate[(size_t)(kd + row) * E_ + c4 * 4];
            wn4[row * 16 + c4] = *(const float4*)&wnoise[(size_t)(kd + row) * E_ + c4 * 4];
        }
        __syncthreads();

        // f32 accumulators for this 64-d tile
        float tc[4][4], tn[4][4];
#pragma unroll
        for (int q = 0; q < 4; ++q)
#pragma unroll
            for (int j = 0; j < 4; ++j) { tc[q][j] = 0.0f; tn[q][j] = 0.0f; }

#pragma unroll 4
        for (int j4 = 0; j4 < 16; ++j4) {
            float4 xa[4];
#pragma unroll
            for (int q = 0; q < 4; ++q) xa[q] = xs4[(ti + 16 * q) * 17 + j4];
#pragma unroll
            for (int jj = 0; jj < 4; ++jj) {
                float4 wgv = wg4[(4 * j4 + jj) * 16 + te];
                float4 wnv = wn4[(4 * j4 + jj) * 16 + te];
                float wg_[4] = { wgv.x, wgv.y, wgv.z, wgv.w };
                float wn_[4] = { wnv.x, wnv.y, wnv.z, wnv.w };
#pragma unroll
                for (int q = 0; q < 4; ++q) {
                    float xv = ((const float*)&xa[q])[jj];
#pragma unroll
                    for (int j = 0; j < 4; ++j) {
                        tc[q][j] = fmaf(xv, wg_[j], tc[q][j]);
                        tn[q][j] = fmaf(xv, wn_[j], tn[q][j]);
                    }
                }
            }
        }
        // fold tile partials into f64 totals
#pragma unroll
        for (int q = 0; q < 4; ++q)
#pragma unroll
            for (int j = 0; j < 4; ++j) {
                acc_c[q][j] += (double)tc[q][j];
                acc_n[q][j] += (double)tn[q][j];
            }
    }

    // ---- per-token: softplus, noisy logits, top-5, gates, load ----
    float loadacc[4] = {0.f, 0.f, 0.f, 0.f};

#pragma unroll 1
    for (int q = 0; q < 4; ++q) {
        int li = ti + 16 * q;   // local token
        int b  = b0 + li;       // global token
        float4 nz = *(const float4*)&noise[(size_t)b * E_ + 4 * te];
        double sd[4], ny[4];
#pragma unroll
        for (int j = 0; j < 4; ++j) {
            double z  = acc_n[q][j];
            double sp = (z > 30.0) ? z : log1p(exp(z));
            sd[j] = sp + 0.01;
            ny[j] = acc_c[q][j] + (double)((const float*)&nz)[j] * sd[j];
        }
        // top-5 across the token's 64 experts (16 lanes x 4 regs)
        double v[4] = { ny[0], ny[1], ny[2], ny[3] };
        double topv[5]; int topi[5];
#pragma unroll 1
        for (int s = 0; s < 5; ++s) {
            double bm = v[0]; int bj = 0;
#pragma unroll
            for (int j = 1; j < 4; ++j) if (v[j] > bm) { bm = v[j]; bj = j; }
            int be = 4 * te + bj;
#pragma unroll
            for (int off = 1; off < 16; off <<= 1) {
                double om = __shfl_xor(bm, off, 64);
                int    oe = __shfl_xor(be, off, 64);
                if (om > bm || (om == bm && oe < be)) { bm = om; be = oe; }
            }
            topv[s] = bm; topi[s] = be;
            if ((be >> 2) == te) v[be & 3] = -1.0e300;   // remove winner from owner lane
        }
        // softmax over top-4
        double m0 = topv[0];
        double e0 = exp(topv[0] - m0), e1 = exp(topv[1] - m0),
               e2 = exp(topv[2] - m0), e3 = exp(topv[3] - m0);
        double inv = 1.0 / (e0 + e1 + e2 + e3);
        float g0 = (float)(e0 * inv), g1 = (float)(e1 * inv),
              g2 = (float)(e2 * inv), g3 = (float)(e3 * inv);
        if (te == 0) {
            s_idx[li][0] = topi[0]; s_idx[li][1] = topi[1];
            s_idx[li][2] = topi[2]; s_idx[li][3] = topi[3];
            s_g[li][0] = g0; s_g[li][1] = g1; s_g[li][2] = g2; s_g[li][3] = g3;
            atomicAdd(&s_imp[topi[0]], g0);
            atomicAdd(&s_imp[topi[1]], g1);
            atomicAdd(&s_imp[topi[2]], g2);
            atomicAdd(&s_imp[topi[3]], g3);
        }
        double thr_out = topv[3];   // 4th largest
        double thr_in  = topv[4];   // 5th largest
#pragma unroll
        for (int j = 0; j < 4; ++j) {
            double thr = (ny[j] > thr_in) ? thr_in : thr_out;
            float  zz  = (float)((acc_c[q][j] - thr) / sd[j]);
            loadacc[j] += 0.5f * (1.0f + erff(zz * 0.70710678118654752f));
        }
    }
#pragma unroll
    for (int j = 0; j < 4; ++j) atomicAdd(&s_load[4 * te + j], loadacc[j]);
    __syncthreads();
    if (t < E_) {
        atomicAdd(&g_imp[t],  s_imp[t]);
        atomicAdd(&g_load[t], s_load[t]);
    }

    // ---- phase B: out[b,:] = sum_k g_k * ctx[idx_k,:]  (write-bound) ----
    for (int li = 0; li < 64; ++li) {
        int   i0 = s_idx[li][0], i1 = s_idx[li][1], i2 = s_idx[li][2], i3 = s_idx[li][3];
        float gg0 = s_g[li][0], gg1 = s_g[li][1], gg2 = s_g[li][2], gg3 = s_g[li][3];
        const f32x4* c0 = (const f32x4*)&ctx[(size_t)i0 * H_];
        const f32x4* c1 = (const f32x4*)&ctx[(size_t)i1 * H_];
        const f32x4* c2 = (const f32x4*)&ctx[(size_t)i2 * H_];
        const f32x4* c3 = (const f32x4*)&ctx[(size_t)i3 * H_];
        f32x4* ob = (f32x4*)&out[(size_t)(b0 + li) * H_];
        for (int f = t; f < H4_; f += 256) {
            f32x4 r = gg0 * c0[f] + gg1 * c1[f] + gg2 * c2[f] + gg3 * c3[f];
            __builtin_nontemporal_store(r, &ob[f]);   // write-once, don't pollute L2
        }
    }
}

__global__ void loss_kernel(const float* __restrict__ g_imp,
                            const float* __restrict__ g_load,
                            float* __restrict__ out)
{
    int e = threadIdx.x;   // 64 threads
    double vi = (double)g_imp[e];
    double vl = (double)g_load[e];
    double si = vi, sl = vl;
#pragma unroll
    for (int off = 1; off < 64; off <<= 1) {
        si += __shfl_xor(si, off, 64);
        sl += __shfl_xor(sl, off, 64);
    }
    double mi = si / 64.0, ml = sl / 64.0;
    double di = vi - mi, dl = vl - ml;
    double qi = di * di, ql = dl * dl;
#pragma unroll
    for (int off = 1; off < 64; off <<= 1) {
        qi += __shfl_xor(qi, off, 64);
        ql += __shfl_xor(ql, off, 64);
    }
    double vari = qi / 64.0, varl = ql / 64.0;
    double cv2i = vari / (mi * mi + 1e-10);
    double cv2l = varl / (ml * ml + 1e-10);
    if (e == 0) out[(size_t)B_ * H_] = (float)((cv2i + cv2l) * 0.01);
}

extern "C" void kernel_launch(void* const* d_in, const int* in_sizes, int n_in,
                              void* d_out, int out_size, void* d_ws, size_t ws_size,
                              hipStream_t stream)
{
    const float* x      = (const float*)d_in[0];
    const float* wgate  = (const float*)d_in[1];
    const float* wnoise = (const float*)d_in[2];
    const float* noise  = (const float*)d_in[3];
    const float* ctx    = (const float*)d_in[4];
    float* out    = (float*)d_out;
    float* g_imp  = (float*)d_ws;
    float* g_load = g_imp + E_;

    (void)hipMemsetAsync(d_ws, 0, 2 * E_ * sizeof(float), stream);
    gate_out_kernel<<<B_ / 64, 256, 0, stream>>>(x, wgate, wnoise, noise, ctx,
                                                 out, g_imp, g_load);
    loss_kernel<<<1, 64, 0, stream>>>(g_imp, g_load, out);
}

// Round 7
// 247.822 us; speedup vs baseline: 1.2540x; 1.2540x over previous
//
#include <hip/hip_runtime.h>
#include <math.h>

#define B_ 32768
#define D_ 512
#define E_ 64
#define H_ 5376
#define H4_ (H_ / 4)

typedef float f32x4 __attribute__((ext_vector_type(4)));
typedef _Float16 f16x8 __attribute__((ext_vector_type(8)));
typedef unsigned int u32x4 __attribute__((ext_vector_type(4)));

__device__ __forceinline__ unsigned short f16bits(_Float16 h) {
    union { _Float16 h; unsigned short u; } c; c.h = h; return c.u;
}

// ---- prep: W' = [wgate|wnoise]^T * 1024, two-term f16 split, [128 cols][512 k] ----
__global__ __launch_bounds__(256) void prep_kernel(
    const float* __restrict__ wgate, const float* __restrict__ wnoise,
    _Float16* __restrict__ wt0, _Float16* __restrict__ wt1)
{
    int e = blockIdx.x;                       // output column 0..127
    const float* src = (e < E_) ? (wgate + e) : (wnoise + (e - E_));
    for (int k = threadIdx.x; k < D_; k += 256) {
        float v = src[(size_t)k * E_] * 1024.0f;
        _Float16 h0 = (_Float16)v;
        _Float16 h1 = (_Float16)(v - (float)h0);   // residual, |.|~2^-12*|v|: normal range
        wt0[(size_t)e * D_ + k] = h0;
        wt1[(size_t)e * D_ + k] = h1;
    }
}

// ---- fused: f16 split-MFMA gating GEMM + top-5 + gates + stats + dispatch ----
// Block = 256 thr = 4 waves, 64 tokens. Wave w owns M-rows w*16..w*16+15.
// accAC[n] = sum x0*(w0+w1)  (scale 2^14); accB[n] = sum x1*w0 (scale 2^26);
// logit = (accAC + accB/4096) / 16384.   n=0..3 gate, n=4..7 noise experts 16n+le.
// C layout (m89): col = lane&15, row = (lane>>4)*4 + reg.
__global__ __launch_bounds__(256) void gate_out_kernel(
    const float* __restrict__ x,
    const _Float16* __restrict__ wt0,
    const _Float16* __restrict__ wt1,
    const float* __restrict__ noise,
    const float* __restrict__ ctx,
    float* __restrict__ out,
    float* __restrict__ g_imp,
    float* __restrict__ g_load)
{
    __shared__ __align__(16) _Float16 x0s[64 * 128];  // 16 KB per K-quarter
    __shared__ __align__(16) _Float16 x1s[64 * 128];  // 16 KB
    __shared__ float s_imp[E_];
    __shared__ float s_load[E_];
    __shared__ int   s_idx[64][4];
    __shared__ float s_g[64][4];

    const int t  = threadIdx.x;
    const int w  = t >> 6;        // wave 0..3
    const int l  = t & 63;        // lane
    const int le = l & 15;
    const int g  = l >> 4;
    const int b0 = blockIdx.x * 64;

    if (t < E_) { s_imp[t] = 0.0f; s_load[t] = 0.0f; }

    f32x4 accAC[8], accB[8];
#pragma unroll
    for (int n = 0; n < 8; ++n) {
        accAC[n] = (f32x4){0.f, 0.f, 0.f, 0.f};
        accB[n]  = (f32x4){0.f, 0.f, 0.f, 0.f};
    }

    const int arow = w * 16 + le;
    for (int q = 0; q < 4; ++q) {
        __syncthreads();   // protect LDS from previous quarter's readers
        // stage x[64 rows][k-quarter 128]: x' = 16x, f16 two-term, XOR-swizzled
#pragma unroll
        for (int i = 0; i < 4; ++i) {
            int id  = t + 256 * i;
            int row = id >> 4;         // 0..63
            int c   = id & 15;         // 16B chunk = 8 k
            const float* src = x + (size_t)(b0 + row) * D_ + q * 128 + c * 8;
            float4 v0 = *(const float4*)src;
            float4 v1 = *(const float4*)(src + 4);
            float vv[8] = {v0.x, v0.y, v0.z, v0.w, v1.x, v1.y, v1.z, v1.w};
            unsigned int hw[4], lw[4];
#pragma unroll
            for (int p = 0; p < 4; ++p) {
                float va = vv[2*p] * 16.0f, vb = vv[2*p+1] * 16.0f;
                _Float16 a0 = (_Float16)va, b0f = (_Float16)vb;
                _Float16 a1 = (_Float16)((va - (float)a0) * 4096.0f);
                _Float16 b1 = (_Float16)((vb - (float)b0f) * 4096.0f);
                hw[p] = (unsigned)f16bits(a0) | ((unsigned)f16bits(b0f) << 16);
                lw[p] = (unsigned)f16bits(a1) | ((unsigned)f16bits(b1) << 16);
            }
            int addr = (row * 256 + c * 16) ^ ((row & 7) << 4);
            *(u32x4*)((char*)x0s + addr) = (u32x4){hw[0], hw[1], hw[2], hw[3]};
            *(u32x4*)((char*)x1s + addr) = (u32x4){lw[0], lw[1], lw[2], lw[3]};
        }
        __syncthreads();
#pragma unroll
        for (int s = 0; s < 4; ++s) {
            int aoff = (arow * 256 + s * 64 + g * 16) ^ ((arow & 7) << 4);
            f16x8 a0 = *(const f16x8*)((const char*)x0s + aoff);
            f16x8 a1 = *(const f16x8*)((const char*)x1s + aoff);
            int ks = q * 4 + s;
#pragma unroll
            for (int n = 0; n < 8; ++n) {
                size_t boff = (size_t)(n * 16 + le) * D_ + ks * 32 + g * 8;
                f16x8 b0 = *(const f16x8*)(wt0 + boff);
                f16x8 b1 = *(const f16x8*)(wt1 + boff);
                accAC[n] = __builtin_amdgcn_mfma_f32_16x16x32_f16(a0, b0, accAC[n], 0, 0, 0);
                accAC[n] = __builtin_amdgcn_mfma_f32_16x16x32_f16(a0, b1, accAC[n], 0, 0, 0);
                accB[n]  = __builtin_amdgcn_mfma_f32_16x16x32_f16(a1, b0, accB[n],  0, 0, 0);
            }
        }
    }

    // ---- epilogue: softplus, noisy logits, top-5, gates, load ----
    const double UNSCALE = 1.0 / 16384.0;       // / (16 * 1024)
    const double RESC    = 1.0 / 4096.0;        // x1 carried *4096
    float loadacc[4] = {0.f, 0.f, 0.f, 0.f};
#pragma unroll
    for (int r = 0; r < 4; ++r) {
        int li = w * 16 + g * 4 + r;   // local token (C row)
        int b  = b0 + li;
        double cl[4], sd[4], ny[4];
#pragma unroll
        for (int n = 0; n < 4; ++n) {
            cl[n] = ((double)accAC[n][r] + (double)accB[n][r] * RESC) * UNSCALE;
            double z = ((double)accAC[n+4][r] + (double)accB[n+4][r] * RESC) * UNSCALE;
            double sp = (z > 30.0) ? z : log1p(exp(z));
            sd[n] = sp + 0.01;
            float nz = noise[(size_t)b * E_ + le + 16 * n];
            ny[n] = cl[n] + (double)nz * sd[n];
        }
        // top-5 over 64 experts (16 lanes x 4 regs; expert id = 16n + le)
        double v[4] = {ny[0], ny[1], ny[2], ny[3]};
        double topv[5]; int topi[5];
#pragma unroll 1
        for (int s5 = 0; s5 < 5; ++s5) {
            double bm = v[0]; int bj = 0;
#pragma unroll
            for (int n = 1; n < 4; ++n) if (v[n] > bm) { bm = v[n]; bj = n; }
            int be = bj * 16 + le;
#pragma unroll
            for (int off = 1; off < 16; off <<= 1) {
                double om = __shfl_xor(bm, off, 64);
                int    oe = __shfl_xor(be, off, 64);
                if (om > bm || (om == bm && oe < be)) { bm = om; be = oe; }
            }
            topv[s5] = bm; topi[s5] = be;
            if ((be & 15) == le) v[be >> 4] = -1.0e300;   // remove winner
        }
        double m0 = topv[0];
        double e0 = exp(topv[0] - m0), e1 = exp(topv[1] - m0),
               e2 = exp(topv[2] - m0), e3 = exp(topv[3] - m0);
        double inv = 1.0 / (e0 + e1 + e2 + e3);
        float g0 = (float)(e0 * inv), g1 = (float)(e1 * inv),
              g2 = (float)(e2 * inv), g3 = (float)(e3 * inv);
        if (le == 0) {
            s_idx[li][0] = topi[0]; s_idx[li][1] = topi[1];
            s_idx[li][2] = topi[2]; s_idx[li][3] = topi[3];
            s_g[li][0] = g0; s_g[li][1] = g1; s_g[li][2] = g2; s_g[li][3] = g3;
            atomicAdd(&s_imp[topi[0]], g0);
            atomicAdd(&s_imp[topi[1]], g1);
            atomicAdd(&s_imp[topi[2]], g2);
            atomicAdd(&s_imp[topi[3]], g3);
        }
        double thr_out = topv[3];   // 4th largest
        double thr_in  = topv[4];   // 5th largest
#pragma unroll
        for (int n = 0; n < 4; ++n) {
            double thr = (ny[n] > thr_in) ? thr_in : thr_out;
            float  zz  = (float)((cl[n] - thr) / sd[n]);
            loadacc[n] += 0.5f * (1.0f + erff(zz * 0.70710678118654752f));
        }
    }
#pragma unroll
    for (int n = 0; n < 4; ++n) atomicAdd(&s_load[16 * n + le], loadacc[n]);
    __syncthreads();
    if (t < E_) {
        atomicAdd(&g_imp[t],  s_imp[t]);
        atomicAdd(&g_load[t], s_load[t]);
    }

    // ---- phase B: out[b,:] = sum_k g_k * ctx[idx_k,:]  (write-bound) ----
    for (int li = 0; li < 64; ++li) {
        int   i0 = s_idx[li][0], i1 = s_idx[li][1], i2 = s_idx[li][2], i3 = s_idx[li][3];
        float gg0 = s_g[li][0], gg1 = s_g[li][1], gg2 = s_g[li][2], gg3 = s_g[li][3];
        const f32x4* c0 = (const f32x4*)&ctx[(size_t)i0 * H_];
        const f32x4* c1 = (const f32x4*)&ctx[(size_t)i1 * H_];
        const f32x4* c2 = (const f32x4*)&ctx[(size_t)i2 * H_];
        const f32x4* c3 = (const f32x4*)&ctx[(size_t)i3 * H_];
        f32x4* ob = (f32x4*)&out[(size_t)(b0 + li) * H_];
        for (int f = t; f < H4_; f += 256) {
            f32x4 r = gg0 * c0[f] + gg1 * c1[f] + gg2 * c2[f] + gg3 * c3[f];
            __builtin_nontemporal_store(r, &ob[f]);   // write-once
        }
    }
}

__global__ void loss_kernel(const float* __restrict__ g_imp,
                            const float* __restrict__ g_load,
                            float* __restrict__ out)
{
    int e = threadIdx.x;   // 64 threads
    double vi = (double)g_imp[e];
    double vl = (double)g_load[e];
    double si = vi, sl = vl;
#pragma unroll
    for (int off = 1; off < 64; off <<= 1) {
        si += __shfl_xor(si, off, 64);
        sl += __shfl_xor(sl, off, 64);
    }
    double mi = si / 64.0, ml = sl / 64.0;
    double di = vi - mi, dl = vl - ml;
    double qi = di * di, ql = dl * dl;
#pragma unroll
    for (int off = 1; off < 64; off <<= 1) {
        qi += __shfl_xor(qi, off, 64);
        ql += __shfl_xor(ql, off, 64);
    }
    double vari = qi / 64.0, varl = ql / 64.0;
    double cv2i = vari / (mi * mi + 1e-10);
    double cv2l = varl / (ml * ml + 1e-10);
    if (e == 0) out[(size_t)B_ * H_] = (float)((cv2i + cv2l) * 0.01);
}

extern "C" void kernel_launch(void* const* d_in, const int* in_sizes, int n_in,
                              void* d_out, int out_size, void* d_ws, size_t ws_size,
                              hipStream_t stream)
{
    const float* x      = (const float*)d_in[0];
    const float* wgate  = (const float*)d_in[1];
    const float* wnoise = (const float*)d_in[2];
    const float* noise  = (const float*)d_in[3];
    const float* ctx    = (const float*)d_in[4];
    float* out    = (float*)d_out;
    float* g_imp  = (float*)d_ws;                     // 64 f32
    float* g_load = g_imp + E_;                       // 64 f32
    _Float16* wt0 = (_Float16*)(g_load + E_);         // 128*512 f16
    _Float16* wt1 = wt0 + 128 * D_;                   // 128*512 f16

    (void)hipMemsetAsync(d_ws, 0, 2 * E_ * sizeof(float), stream);
    prep_kernel<<<128, 256, 0, stream>>>(wgate, wnoise, wt0, wt1);
    gate_out_kernel<<<B_ / 64, 256, 0, stream>>>(x, wt0, wt1, noise, ctx,
                                                 out, g_imp, g_load);
    loss_kernel<<<1, 64, 0, stream>>>(g_imp, g_load, out);
}

// Round 8
// 243.242 us; speedup vs baseline: 1.2776x; 1.0188x over previous
//
#include <hip/hip_runtime.h>
#include <math.h>

#define B_ 32768
#define D_ 512
#define E_ 64
#define H_ 5376
#define H4_ (H_ / 4)

typedef float f32x4 __attribute__((ext_vector_type(4)));
typedef _Float16 f16x8 __attribute__((ext_vector_type(8)));
typedef unsigned int u32x4 __attribute__((ext_vector_type(4)));

__device__ __forceinline__ unsigned short f16bits(_Float16 h) {
    union { _Float16 h; unsigned short u; } c; c.h = h; return c.u;
}

// ---- prep: W' = [wgate|wnoise]^T * 1024, two-term f16 split, [128 cols][512 k] ----
__global__ __launch_bounds__(256) void prep_kernel(
    const float* __restrict__ wgate, const float* __restrict__ wnoise,
    _Float16* __restrict__ wt0, _Float16* __restrict__ wt1)
{
    int e = blockIdx.x;                       // output column 0..127
    const float* src = (e < E_) ? (wgate + e) : (wnoise + (e - E_));
    for (int k = threadIdx.x; k < D_; k += 256) {
        float v = src[(size_t)k * E_] * 1024.0f;
        _Float16 h0 = (_Float16)v;
        _Float16 h1 = (_Float16)(v - (float)h0);
        wt0[(size_t)e * D_ + k] = h0;
        wt1[(size_t)e * D_ + k] = h1;
    }
}

// ---- gate: f16 split-MFMA GEMM + top-5 + gates + stats (no dispatch) ----
// Block = 256 thr = 4 waves, 64 tokens. Wave w owns M-rows w*16..w*16+15.
// accAC[n] = sum x0*(w0+w1) (scale 2^14); accB[n] = sum x1*w0 (scale 2^26);
// logit = (accAC + accB/4096)/16384.  n=0..3 gate, n=4..7 noise experts 16n+le.
// C layout (m89): col = lane&15, row = (lane>>4)*4 + reg.
__global__ __launch_bounds__(256) void gate_kernel(
    const float* __restrict__ x,
    const _Float16* __restrict__ wt0,
    const _Float16* __restrict__ wt1,
    const float* __restrict__ noise,
    unsigned int* __restrict__ o_idx,   // packed 4x u8 expert ids per token
    float4* __restrict__ o_g,           // 4 gates per token
    float* __restrict__ g_imp,
    float* __restrict__ g_load)
{
    __shared__ __align__(16) _Float16 x0s[64 * 128];  // 16 KB per K-quarter
    __shared__ __align__(16) _Float16 x1s[64 * 128];  // 16 KB
    __shared__ float s_imp[E_];
    __shared__ float s_load[E_];

    const int t  = threadIdx.x;
    const int w  = t >> 6;        // wave 0..3
    const int l  = t & 63;        // lane
    const int le = l & 15;
    const int g  = l >> 4;
    const int b0 = blockIdx.x * 64;

    if (t < E_) { s_imp[t] = 0.0f; s_load[t] = 0.0f; }

    f32x4 accAC[8], accB[8];
#pragma unroll
    for (int n = 0; n < 8; ++n) {
        accAC[n] = (f32x4){0.f, 0.f, 0.f, 0.f};
        accB[n]  = (f32x4){0.f, 0.f, 0.f, 0.f};
    }

    const int arow = w * 16 + le;
    for (int q = 0; q < 4; ++q) {
        __syncthreads();   // protect LDS from previous quarter's readers
#pragma unroll
        for (int i = 0; i < 4; ++i) {
            int id  = t + 256 * i;
            int row = id >> 4;
            int c   = id & 15;
            const float* src = x + (size_t)(b0 + row) * D_ + q * 128 + c * 8;
            float4 v0 = *(const float4*)src;
            float4 v1 = *(const float4*)(src + 4);
            float vv[8] = {v0.x, v0.y, v0.z, v0.w, v1.x, v1.y, v1.z, v1.w};
            unsigned int hw[4], lw[4];
#pragma unroll
            for (int p = 0; p < 4; ++p) {
                float va = vv[2*p] * 16.0f, vb = vv[2*p+1] * 16.0f;
                _Float16 a0 = (_Float16)va, b0f = (_Float16)vb;
                _Float16 a1 = (_Float16)((va - (float)a0) * 4096.0f);
                _Float16 b1 = (_Float16)((vb - (float)b0f) * 4096.0f);
                hw[p] = (unsigned)f16bits(a0) | ((unsigned)f16bits(b0f) << 16);
                lw[p] = (unsigned)f16bits(a1) | ((unsigned)f16bits(b1) << 16);
            }
            int addr = (row * 256 + c * 16) ^ ((row & 7) << 4);
            *(u32x4*)((char*)x0s + addr) = (u32x4){hw[0], hw[1], hw[2], hw[3]};
            *(u32x4*)((char*)x1s + addr) = (u32x4){lw[0], lw[1], lw[2], lw[3]};
        }
        __syncthreads();
#pragma unroll
        for (int s = 0; s < 4; ++s) {
            int aoff = (arow * 256 + s * 64 + g * 16) ^ ((arow & 7) << 4);
            f16x8 a0 = *(const f16x8*)((const char*)x0s + aoff);
            f16x8 a1 = *(const f16x8*)((const char*)x1s + aoff);
            int ks = q * 4 + s;
#pragma unroll
            for (int n = 0; n < 8; ++n) {
                size_t boff = (size_t)(n * 16 + le) * D_ + ks * 32 + g * 8;
                f16x8 b0 = *(const f16x8*)(wt0 + boff);
                f16x8 b1 = *(const f16x8*)(wt1 + boff);
                accAC[n] = __builtin_amdgcn_mfma_f32_16x16x32_f16(a0, b0, accAC[n], 0, 0, 0);
                accAC[n] = __builtin_amdgcn_mfma_f32_16x16x32_f16(a0, b1, accAC[n], 0, 0, 0);
                accB[n]  = __builtin_amdgcn_mfma_f32_16x16x32_f16(a1, b0, accB[n],  0, 0, 0);
            }
        }
    }

    // ---- epilogue: softplus, noisy logits, top-5, gates, load ----
    const double UNSCALE = 1.0 / 16384.0;
    const double RESC    = 1.0 / 4096.0;
    float loadacc[4] = {0.f, 0.f, 0.f, 0.f};
#pragma unroll
    for (int r = 0; r < 4; ++r) {
        int li = w * 16 + g * 4 + r;   // local token (C row)
        int b  = b0 + li;
        double cl[4], sd[4], ny[4];
#pragma unroll
        for (int n = 0; n < 4; ++n) {
            cl[n] = ((double)accAC[n][r] + (double)accB[n][r] * RESC) * UNSCALE;
            double z = ((double)accAC[n+4][r] + (double)accB[n+4][r] * RESC) * UNSCALE;
            double sp = (z > 30.0) ? z : log1p(exp(z));
            sd[n] = sp + 0.01;
            float nz = noise[(size_t)b * E_ + le + 16 * n];
            ny[n] = cl[n] + (double)nz * sd[n];
        }
        double v[4] = {ny[0], ny[1], ny[2], ny[3]};
        double topv[5]; int topi[5];
#pragma unroll 1
        for (int s5 = 0; s5 < 5; ++s5) {
            double bm = v[0]; int bj = 0;
#pragma unroll
            for (int n = 1; n < 4; ++n) if (v[n] > bm) { bm = v[n]; bj = n; }
            int be = bj * 16 + le;
#pragma unroll
            for (int off = 1; off < 16; off <<= 1) {
                double om = __shfl_xor(bm, off, 64);
                int    oe = __shfl_xor(be, off, 64);
                if (om > bm || (om == bm && oe < be)) { bm = om; be = oe; }
            }
            topv[s5] = bm; topi[s5] = be;
            if ((be & 15) == le) v[be >> 4] = -1.0e300;
        }
        double m0 = topv[0];
        double e0 = exp(topv[0] - m0), e1 = exp(topv[1] - m0),
               e2 = exp(topv[2] - m0), e3 = exp(topv[3] - m0);
        double inv = 1.0 / (e0 + e1 + e2 + e3);
        float g0 = (float)(e0 * inv), g1 = (float)(e1 * inv),
              g2 = (float)(e2 * inv), g3 = (float)(e3 * inv);
        if (le == 0) {
            o_idx[b] = (unsigned)topi[0] | ((unsigned)topi[1] << 8) |
                       ((unsigned)topi[2] << 16) | ((unsigned)topi[3] << 24);
            float4 gv; gv.x = g0; gv.y = g1; gv.z = g2; gv.w = g3;
            o_g[b] = gv;
            atomicAdd(&s_imp[topi[0]], g0);
            atomicAdd(&s_imp[topi[1]], g1);
            atomicAdd(&s_imp[topi[2]], g2);
            atomicAdd(&s_imp[topi[3]], g3);
        }
        double thr_out = topv[3];
        double thr_in  = topv[4];
#pragma unroll
        for (int n = 0; n < 4; ++n) {
            double thr = (ny[n] > thr_in) ? thr_in : thr_out;
            float  zz  = (float)((cl[n] - thr) / sd[n]);
            loadacc[n] += 0.5f * (1.0f + erff(zz * 0.70710678118654752f));
        }
    }
#pragma unroll
    for (int n = 0; n < 4; ++n) atomicAdd(&s_load[16 * n + le], loadacc[n]);
    __syncthreads();
    if (t < E_) {
        atomicAdd(&g_imp[t],  s_imp[t]);
        atomicAdd(&g_load[t], s_load[t]);
    }
}

// ---- dispatch: out[b,:] = sum_k g_k * ctx[idx_k,:]. 4096 blocks, 8 tokens each,
// 2-token ILP (8 loads + 2 stores in flight per iteration), minimal VGPR/LDS ->
// 8 blocks/CU = 32 waves/CU of memory-level parallelism.
__global__ __launch_bounds__(256) void dispatch_kernel(
    const float* __restrict__ ctx,
    const unsigned int* __restrict__ o_idx,
    const float4* __restrict__ o_g,
    float* __restrict__ out)
{
    const int t = threadIdx.x;
    const int tb0 = blockIdx.x * 8;
#pragma unroll 1
    for (int s = 0; s < 8; s += 2) {
        int ba = tb0 + s, bb = ba + 1;
        unsigned pka = o_idx[ba], pkb = o_idx[bb];
        float4 ga = o_g[ba], gb = o_g[bb];
        const f32x4* a0 = (const f32x4*)&ctx[(size_t)(pka & 255u) * H_];
        const f32x4* a1 = (const f32x4*)&ctx[(size_t)((pka >> 8) & 255u) * H_];
        const f32x4* a2 = (const f32x4*)&ctx[(size_t)((pka >> 16) & 255u) * H_];
        const f32x4* a3 = (const f32x4*)&ctx[(size_t)(pka >> 24) * H_];
        const f32x4* c0 = (const f32x4*)&ctx[(size_t)(pkb & 255u) * H_];
        const f32x4* c1 = (const f32x4*)&ctx[(size_t)((pkb >> 8) & 255u) * H_];
        const f32x4* c2 = (const f32x4*)&ctx[(size_t)((pkb >> 16) & 255u) * H_];
        const f32x4* c3 = (const f32x4*)&ctx[(size_t)(pkb >> 24) * H_];
        f32x4* oa = (f32x4*)&out[(size_t)ba * H_];
        f32x4* ob = (f32x4*)&out[(size_t)bb * H_];
        for (int f = t; f < H4_; f += 256) {
            f32x4 ra = ga.x * a0[f] + ga.y * a1[f] + ga.z * a2[f] + ga.w * a3[f];
            f32x4 rb = gb.x * c0[f] + gb.y * c1[f] + gb.z * c2[f] + gb.w * c3[f];
            __builtin_nontemporal_store(ra, &oa[f]);
            __builtin_nontemporal_store(rb, &ob[f]);
        }
    }
}

__global__ void loss_kernel(const float* __restrict__ g_imp,
                            const float* __restrict__ g_load,
                            float* __restrict__ out)
{
    int e = threadIdx.x;   // 64 threads
    double vi = (double)g_imp[e];
    double vl = (double)g_load[e];
    double si = vi, sl = vl;
#pragma unroll
    for (int off = 1; off < 64; off <<= 1) {
        si += __shfl_xor(si, off, 64);
        sl += __shfl_xor(sl, off, 64);
    }
    double mi = si / 64.0, ml = sl / 64.0;
    double di = vi - mi, dl = vl - ml;
    double qi = di * di, ql = dl * dl;
#pragma unroll
    for (int off = 1; off < 64; off <<= 1) {
        qi += __shfl_xor(qi, off, 64);
        ql += __shfl_xor(ql, off, 64);
    }
    double vari = qi / 64.0, varl = ql / 64.0;
    double cv2i = vari / (mi * mi + 1e-10);
    double cv2l = varl / (ml * ml + 1e-10);
    if (e == 0) out[(size_t)B_ * H_] = (float)((cv2i + cv2l) * 0.01);
}

extern "C" void kernel_launch(void* const* d_in, const int* in_sizes, int n_in,
                              void* d_out, int out_size, void* d_ws, size_t ws_size,
                              hipStream_t stream)
{
    const float* x      = (const float*)d_in[0];
    const float* wgate  = (const float*)d_in[1];
    const float* wnoise = (const float*)d_in[2];
    const float* noise  = (const float*)d_in[3];
    const float* ctx    = (const float*)d_in[4];
    float* out    = (float*)d_out;
    float* g_imp  = (float*)d_ws;                     // 64 f32
    float* g_load = g_imp + E_;                       // 64 f32
    _Float16* wt0 = (_Float16*)(g_load + E_);         // 128*512 f16
    _Float16* wt1 = wt0 + 128 * D_;                   // 128*512 f16
    unsigned int* o_idx = (unsigned int*)(wt1 + 128 * D_);  // 32768 u32
    float4* o_g = (float4*)(o_idx + B_);                    // 32768 float4

    (void)hipMemsetAsync(d_ws, 0, 2 * E_ * sizeof(float), stream);
    prep_kernel<<<128, 256, 0, stream>>>(wgate, wnoise, wt0, wt1);
    gate_kernel<<<B_ / 64, 256, 0, stream>>>(x, wt0, wt1, noise,
                                             o_idx, o_g, g_imp, g_load);
    dispatch_kernel<<<B_ / 8, 256, 0, stream>>>(ctx, o_idx, o_g, out);
    loss_kernel<<<1, 64, 0, stream>>>(g_imp, g_load, out);
}

// Round 9
// 242.659 us; speedup vs baseline: 1.2807x; 1.0024x over previous
//
#include <hip/hip_runtime.h>
#include <math.h>

#define B_ 32768
#define D_ 512
#define E_ 64
#define H_ 5376
#define H4_ (H_ / 4)
#define HC_ 128            // floats per dispatch H-chunk
#define NCH_ (H_ / HC_)    // 42 chunks

typedef float f32x4 __attribute__((ext_vector_type(4)));
typedef _Float16 f16x8 __attribute__((ext_vector_type(8)));
typedef unsigned int u32x4 __attribute__((ext_vector_type(4)));

__device__ __forceinline__ unsigned short f16bits(_Float16 h) {
    union { _Float16 h; unsigned short u; } c; c.h = h; return c.u;
}

// ---- prep: W' = [wgate|wnoise]^T * 1024, two-term f16 split, [128 cols][512 k] ----
__global__ __launch_bounds__(256) void prep_kernel(
    const float* __restrict__ wgate, const float* __restrict__ wnoise,
    _Float16* __restrict__ wt0, _Float16* __restrict__ wt1)
{
    int e = blockIdx.x;                       // output column 0..127
    const float* src = (e < E_) ? (wgate + e) : (wnoise + (e - E_));
    for (int k = threadIdx.x; k < D_; k += 256) {
        float v = src[(size_t)k * E_] * 1024.0f;
        _Float16 h0 = (_Float16)v;
        _Float16 h1 = (_Float16)(v - (float)h0);
        wt0[(size_t)e * D_ + k] = h0;
        wt1[(size_t)e * D_ + k] = h1;
    }
}

// ---- gate: f16 split-MFMA GEMM + top-5 + gates + stats ----
// Block = 256 thr = 4 waves, 64 tokens. Wave w owns M-rows w*16..w*16+15.
// accAC[n] = sum x0*(w0+w1) (scale 2^14); accB[n] = sum x1*w0 (scale 2^26);
// logit = (accAC + accB/4096)/16384.  n=0..3 gate, n=4..7 noise experts 16n+le.
// C layout (m89): col = lane&15, row = (lane>>4)*4 + reg.
__global__ __launch_bounds__(256) void gate_kernel(
    const float* __restrict__ x,
    const _Float16* __restrict__ wt0,
    const _Float16* __restrict__ wt1,
    const float* __restrict__ noise,
    unsigned int* __restrict__ o_idx,   // packed 4x u8 expert ids per token
    float4* __restrict__ o_g,           // 4 gates per token
    float* __restrict__ g_imp,
    float* __restrict__ g_load)
{
    __shared__ __align__(16) _Float16 x0s[64 * 128];  // 16 KB per K-quarter
    __shared__ __align__(16) _Float16 x1s[64 * 128];  // 16 KB
    __shared__ float s_imp[E_];
    __shared__ float s_load[E_];

    const int t  = threadIdx.x;
    const int w  = t >> 6;        // wave 0..3
    const int l  = t & 63;        // lane
    const int le = l & 15;
    const int g  = l >> 4;
    const int b0 = blockIdx.x * 64;

    if (t < E_) { s_imp[t] = 0.0f; s_load[t] = 0.0f; }

    f32x4 accAC[8], accB[8];
#pragma unroll
    for (int n = 0; n < 8; ++n) {
        accAC[n] = (f32x4){0.f, 0.f, 0.f, 0.f};
        accB[n]  = (f32x4){0.f, 0.f, 0.f, 0.f};
    }

    const int arow = w * 16 + le;
    for (int q = 0; q < 4; ++q) {
        __syncthreads();   // protect LDS from previous quarter's readers
#pragma unroll
        for (int i = 0; i < 4; ++i) {
            int id  = t + 256 * i;
            int row = id >> 4;
            int c   = id & 15;
            const float* src = x + (size_t)(b0 + row) * D_ + q * 128 + c * 8;
            float4 v0 = *(const float4*)src;
            float4 v1 = *(const float4*)(src + 4);
            float vv[8] = {v0.x, v0.y, v0.z, v0.w, v1.x, v1.y, v1.z, v1.w};
            unsigned int hw[4], lw[4];
#pragma unroll
            for (int p = 0; p < 4; ++p) {
                float va = vv[2*p] * 16.0f, vb = vv[2*p+1] * 16.0f;
                _Float16 a0 = (_Float16)va, b0f = (_Float16)vb;
                _Float16 a1 = (_Float16)((va - (float)a0) * 4096.0f);
                _Float16 b1 = (_Float16)((vb - (float)b0f) * 4096.0f);
                hw[p] = (unsigned)f16bits(a0) | ((unsigned)f16bits(b0f) << 16);
                lw[p] = (unsigned)f16bits(a1) | ((unsigned)f16bits(b1) << 16);
            }
            int addr = (row * 256 + c * 16) ^ ((row & 7) << 4);
            *(u32x4*)((char*)x0s + addr) = (u32x4){hw[0], hw[1], hw[2], hw[3]};
            *(u32x4*)((char*)x1s + addr) = (u32x4){lw[0], lw[1], lw[2], lw[3]};
        }
        __syncthreads();
#pragma unroll
        for (int s = 0; s < 4; ++s) {
            int aoff = (arow * 256 + s * 64 + g * 16) ^ ((arow & 7) << 4);
            f16x8 a0 = *(const f16x8*)((const char*)x0s + aoff);
            f16x8 a1 = *(const f16x8*)((const char*)x1s + aoff);
            int ks = q * 4 + s;
#pragma unroll
            for (int n = 0; n < 8; ++n) {
                size_t boff = (size_t)(n * 16 + le) * D_ + ks * 32 + g * 8;
                f16x8 b0 = *(const f16x8*)(wt0 + boff);
                f16x8 b1 = *(const f16x8*)(wt1 + boff);
                accAC[n] = __builtin_amdgcn_mfma_f32_16x16x32_f16(a0, b0, accAC[n], 0, 0, 0);
                accAC[n] = __builtin_amdgcn_mfma_f32_16x16x32_f16(a0, b1, accAC[n], 0, 0, 0);
                accB[n]  = __builtin_amdgcn_mfma_f32_16x16x32_f16(a1, b0, accB[n],  0, 0, 0);
            }
        }
    }

    // ---- epilogue: softplus, noisy logits, top-5, gates, load ----
    const double UNSCALE = 1.0 / 16384.0;
    const double RESC    = 1.0 / 4096.0;
    float loadacc[4] = {0.f, 0.f, 0.f, 0.f};
#pragma unroll
    for (int r = 0; r < 4; ++r) {
        int li = w * 16 + g * 4 + r;   // local token (C row)
        int b  = b0 + li;
        double cl[4], sd[4], ny[4];
#pragma unroll
        for (int n = 0; n < 4; ++n) {
            cl[n] = ((double)accAC[n][r] + (double)accB[n][r] * RESC) * UNSCALE;
            double z = ((double)accAC[n+4][r] + (double)accB[n+4][r] * RESC) * UNSCALE;
            double sp = (z > 30.0) ? z : log1p(exp(z));
            sd[n] = sp + 0.01;
            float nz = noise[(size_t)b * E_ + le + 16 * n];
            ny[n] = cl[n] + (double)nz * sd[n];
        }
        double v[4] = {ny[0], ny[1], ny[2], ny[3]};
        double topv[5]; int topi[5];
#pragma unroll 1
        for (int s5 = 0; s5 < 5; ++s5) {
            double bm = v[0]; int bj = 0;
#pragma unroll
            for (int n = 1; n < 4; ++n) if (v[n] > bm) { bm = v[n]; bj = n; }
            int be = bj * 16 + le;
#pragma unroll
            for (int off = 1; off < 16; off <<= 1) {
                double om = __shfl_xor(bm, off, 64);
                int    oe = __shfl_xor(be, off, 64);
                if (om > bm || (om == bm && oe < be)) { bm = om; be = oe; }
            }
            topv[s5] = bm; topi[s5] = be;
            if ((be & 15) == le) v[be >> 4] = -1.0e300;
        }
        double m0 = topv[0];
        double e0 = exp(topv[0] - m0), e1 = exp(topv[1] - m0),
               e2 = exp(topv[2] - m0), e3 = exp(topv[3] - m0);
        double inv = 1.0 / (e0 + e1 + e2 + e3);
        float g0 = (float)(e0 * inv), g1 = (float)(e1 * inv),
              g2 = (float)(e2 * inv), g3 = (float)(e3 * inv);
        if (le == 0) {
            o_idx[b] = (unsigned)topi[0] | ((unsigned)topi[1] << 8) |
                       ((unsigned)topi[2] << 16) | ((unsigned)topi[3] << 24);
            float4 gv; gv.x = g0; gv.y = g1; gv.z = g2; gv.w = g3;
            o_g[b] = gv;
            atomicAdd(&s_imp[topi[0]], g0);
            atomicAdd(&s_imp[topi[1]], g1);
            atomicAdd(&s_imp[topi[2]], g2);
            atomicAdd(&s_imp[topi[3]], g3);
        }
        double thr_out = topv[3];
        double thr_in  = topv[4];
#pragma unroll
        for (int n = 0; n < 4; ++n) {
            double thr = (ny[n] > thr_in) ? thr_in : thr_out;
            float  zz  = (float)((cl[n] - thr) / sd[n]);
            loadacc[n] += 0.5f * (1.0f + erff(zz * 0.70710678118654752f));
        }
    }
#pragma unroll
    for (int n = 0; n < 4; ++n) atomicAdd(&s_load[16 * n + le], loadacc[n]);
    __syncthreads();
    if (t < E_) {
        atomicAdd(&g_imp[t],  s_imp[t]);
        atomicAdd(&g_load[t], s_load[t]);
    }
}

// ---- dispatch v2: LDS-staged sparse GEMM tiling ----
// Grid (NCH_, 512): block = (H-chunk ch, token-group tg). Stage
// ctx[64 experts][128 floats] (32 KB) in LDS once; all 64 tokens gather
// their 4 expert rows from LDS. Global reads drop 4x -> ~1 B read / B written.
// 5 blocks/CU (LDS-limited) = 20 waves/CU.
__global__ __launch_bounds__(256) void dispatch_kernel(
    const float* __restrict__ ctx,
    const unsigned int* __restrict__ o_idx,
    const float4* __restrict__ o_g,
    float* __restrict__ out)
{
    __shared__ f32x4 cs[E_ * (HC_ / 4)];   // [64 experts][32 float4] = 32 KB

    const int t  = threadIdx.x;
    const int h0 = blockIdx.x * HC_;       // float offset of chunk
    const int tb = blockIdx.y * 64;        // first token of group

    // stage ctx[*, h0:h0+128] -> LDS (64 rows x 512 B, coalesced per row)
#pragma unroll
    for (int i = 0; i < 8; ++i) {
        int idx = t + 256 * i;             // 0..2047
        int e = idx >> 5, c = idx & 31;
        cs[idx] = *(const f32x4*)&ctx[(size_t)e * H_ + h0 + c * 4];
    }
    __syncthreads();

    const int tok = t >> 5;                // 0..7
    const int c   = t & 31;
#pragma unroll
    for (int s = 0; s < 8; ++s) {
        int b = tb + s * 8 + tok;
        unsigned pk = o_idx[b];            // 32 lanes same addr -> broadcast
        float4 g = o_g[b];
        f32x4 r = g.x * cs[((pk      ) & 255u) * 32 + c]
                + g.y * cs[((pk >>  8) & 255u) * 32 + c]
                + g.z * cs[((pk >> 16) & 255u) * 32 + c]
                + g.w * cs[( pk >> 24         ) * 32 + c];
        __builtin_nontemporal_store(r, (f32x4*)&out[(size_t)b * H_ + h0 + c * 4]);
    }
}

__global__ void loss_kernel(const float* __restrict__ g_imp,
                            const float* __restrict__ g_load,
                            float* __restrict__ out)
{
    int e = threadIdx.x;   // 64 threads
    double vi = (double)g_imp[e];
    double vl = (double)g_load[e];
    double si = vi, sl = vl;
#pragma unroll
    for (int off = 1; off < 64; off <<= 1) {
        si += __shfl_xor(si, off, 64);
        sl += __shfl_xor(sl, off, 64);
    }
    double mi = si / 64.0, ml = sl / 64.0;
    double di = vi - mi, dl = vl - ml;
    double qi = di * di, ql = dl * dl;
#pragma unroll
    for (int off = 1; off < 64; off <<= 1) {
        qi += __shfl_xor(qi, off, 64);
        ql += __shfl_xor(ql, off, 64);
    }
    double vari = qi / 64.0, varl = ql / 64.0;
    double cv2i = vari / (mi * mi + 1e-10);
    double cv2l = varl / (ml * ml + 1e-10);
    if (e == 0) out[(size_t)B_ * H_] = (float)((cv2i + cv2l) * 0.01);
}

extern "C" void kernel_launch(void* const* d_in, const int* in_sizes, int n_in,
                              void* d_out, int out_size, void* d_ws, size_t ws_size,
                              hipStream_t stream)
{
    const float* x      = (const float*)d_in[0];
    const float* wgate  = (const float*)d_in[1];
    const float* wnoise = (const float*)d_in[2];
    const float* noise  = (const float*)d_in[3];
    const float* ctx    = (const float*)d_in[4];
    float* out    = (float*)d_out;
    float* g_imp  = (float*)d_ws;                     // 64 f32
    float* g_load = g_imp + E_;                       // 64 f32
    _Float16* wt0 = (_Float16*)(g_load + E_);         // 128*512 f16
    _Float16* wt1 = wt0 + 128 * D_;                   // 128*512 f16
    unsigned int* o_idx = (unsigned int*)(wt1 + 128 * D_);  // 32768 u32
    float4* o_g = (float4*)(o_idx + B_);                    // 32768 float4

    (void)hipMemsetAsync(d_ws, 0, 2 * E_ * sizeof(float), stream);
    prep_kernel<<<128, 256, 0, stream>>>(wgate, wnoise, wt0, wt1);
    gate_kernel<<<B_ / 64, 256, 0, stream>>>(x, wt0, wt1, noise,
                                             o_idx, o_g, g_imp, g_load);
    dispatch_kernel<<<dim3(NCH_, B_ / 64), 256, 0, stream>>>(ctx, o_idx, o_g, out);
    loss_kernel<<<1, 64, 0, stream>>>(g_imp, g_load, out);
}